// Round 1
// baseline (22977.934 us; speedup 1.0000x reference)
//
#include <hip/hip_runtime.h>

// Handwriting synthesis RNN (Graves attention) — persistent fused kernel.
// Design: 4 independent batch-groups of 16; per-group 50-block epoch barrier
// once per timestep; LSTM2 lags 1 step, MDN lags 2; attention recomputed
// redundantly per consumer block (keeps it off a second barrier).
// All GEMMs: bf16 MFMA 16x16x32, f32 accum/state.  WS use ~7.7 MB.

typedef unsigned short u16;
typedef unsigned char  u8;
typedef unsigned int   u32;
typedef u16   u16x8  __attribute__((ext_vector_type(8)));
typedef __bf16 bf16x8 __attribute__((ext_vector_type(8)));
typedef float f32x4  __attribute__((ext_vector_type(4)));

#define DEV static __device__ __forceinline__

// problem constants
#define BT   64
#define TT   800
#define UU   64
#define HH   512
#define KMIX 10
#define SENT 60
#define NG   2048
#define MOUT 121
// packed K sizes (column order chosen for aligned staging; see pack_kernel)
#define K1P 576    // X1 = [h1:512][strk:3][w:60][pad:1]
#define K2P 1088   // X2 = [h1:512][h2:512][strk:3][w:60][pad:1]
#define KMD 1024   // Xm = [h1:512][h2:512]
#define KSW 512

#define NBG 4
#define G1B 16     // gates1 blocks per bg (128 packed cols each)
#define G2B 32     // gates2 blocks per bg (64 packed cols each)
#define MDB 2      // mdn blocks per bg (64 cols each)
#define BPG (G1B + G2B + MDB)   // 50
#define NBLK (NBG * BPG)        // 200
#define NITER 802

// workspace layout (bytes); all 256-aligned
#define OFF_BAR 0
#define OFF_H1  4096
#define OFF_H2  (OFF_H1 + 4*BT*HH*2)
#define OFF_IDX (OFF_H2 + 4*BT*HH*2)
#define OFF_W1  (OFF_IDX + 4096)
#define OFF_W2  (OFF_W1 + NG*K1P*2)
#define OFF_WSW (OFF_W2 + NG*K2P*2)
#define OFF_WMD (OFF_WSW + 32*KSW*2)
#define OFF_B1  (OFF_WMD + 128*KMD*2)
#define OFF_B2  (OFF_B1 + NG*4)
#define OFF_BSW (OFF_B2 + NG*4)
#define OFF_BMD (OFF_BSW + 256)
#define WS_NEED (OFF_BMD + 512)
#define ZERO_BYTES OFF_IDX   // barrier + h1/h2 rings

// output offsets (floats), reference return order
#define OW_EOS 0
#define OW_W   (BT*TT)
#define OW_MU1 (OW_W   + BT*TT*20)
#define OW_MU2 (OW_MU1 + BT*TT*20)
#define OW_S1  (OW_MU2 + BT*TT*20)
#define OW_S2  (OW_S1  + BT*TT*20)
#define OW_RHO (OW_S2  + BT*TT*20)

DEV u16 f2bf(float f){
  u32 u = __builtin_bit_cast(u32, f);
  u = (u + 0x7FFFu + ((u >> 16) & 1u)) >> 16;
  return (u16)u;
}
DEV bf16x8 ld8(const u16* p){ return __builtin_bit_cast(bf16x8, *(const u16x8*)p); }
DEV f32x4 mfma16(bf16x8 a, bf16x8 b, f32x4 c){
  return __builtin_amdgcn_mfma_f32_16x16x32_bf16(a, b, c, 0, 0, 0);
}
DEV float sig_(float x){ return 1.f/(1.f + __expf(-x)); }
DEV float tanh_(float x){
  float ax = fabsf(x);
  float e  = __expf(-2.f*ax);
  float t2 = (1.f - e)/(1.f + e);
  return x < 0.f ? -t2 : t2;
}

// ---------------- weight/bias/index pre-pack ----------------
__global__ __launch_bounds__(256) void pack_kernel(
    const float* __restrict__ Wih1, const float* __restrict__ Whh1,
    const float* __restrict__ bih1, const float* __restrict__ bhh1,
    const float* __restrict__ Wih2, const float* __restrict__ Whh2,
    const float* __restrict__ bih2, const float* __restrict__ bhh2,
    const float* __restrict__ Wsw,  const float* __restrict__ bsw,
    const float* __restrict__ Wmdn, const float* __restrict__ bmdn,
    const float* __restrict__ onehots, char* __restrict__ ws)
{
  u16* Wp1  = (u16*)(ws + OFF_W1);
  u16* Wp2  = (u16*)(ws + OFF_W2);
  u16* Wswp = (u16*)(ws + OFF_WSW);
  u16* Wmdp = (u16*)(ws + OFF_WMD);
  float* b1p  = (float*)(ws + OFF_B1);
  float* b2p  = (float*)(ws + OFF_B2);
  float* bswp = (float*)(ws + OFF_BSW);
  float* bmdp = (float*)(ws + OFF_BMD);
  u8* idx8 = (u8*)(ws + OFF_IDX);

  const int SA = NG*K1P, SB = NG*K2P, SC = 32*KSW, SD = 128*KMD;
  const int SE = NG + NG + 32 + 128, SF = BT*UU;
  const int total = SA+SB+SC+SD+SE+SF;
  for (int i = blockIdx.x*blockDim.x + threadIdx.x; i < total; i += gridDim.x*blockDim.x){
    if (i < SA){
      // packed gate col n = hdim*4 + gate ; original row r = gate*512 + hdim
      const int n = i / K1P, k = i - n*K1P;
      const int r = (n&3)*HH + (n>>2);
      float f;
      if (k < 512)      f = Whh1[r*HH + k];
      else if (k < 515) f = Wih1[r*63 + (k-512)];        // strks cols 0..2
      else if (k < 575) f = Wih1[r*63 + 3 + (k-515)];    // w cols 3..62
      else              f = 0.f;
      Wp1[i] = f2bf(f);
    } else if (i < SA+SB){
      const int j = i - SA;
      const int n = j / K2P, k = j - n*K2P;
      const int r = (n&3)*HH + (n>>2);
      float f;
      if (k < 512)       f = Wih2[r*575 + 3 + k];            // hid1
      else if (k < 1024) f = Whh2[r*HH + (k-512)];           // h2 recur
      else if (k < 1027) f = Wih2[r*575 + (k-1024)];         // strks
      else if (k < 1087) f = Wih2[r*575 + 515 + (k-1027)];   // win
      else               f = 0.f;
      Wp2[j] = f2bf(f);
    } else if (i < SA+SB+SC){
      const int j = i - SA - SB;
      const int n = j >> 9, k = j & 511;
      Wswp[j] = f2bf(n < 30 ? Wsw[n*KSW + k] : 0.f);
    } else if (i < SA+SB+SC+SD){
      const int j = i - SA - SB - SC;
      const int n = j >> 10, k = j & 1023;
      float f = 0.f;
      if (n < MOUT) f = (k < 512) ? Wmdn[n*1536 + k]
                                  : (Wmdn[n*1536 + 512 + (k-512)] + Wmdn[n*1536 + 1024 + (k-512)]);
      Wmdp[j] = f2bf(f);
    } else if (i < SA+SB+SC+SD+SE){
      int j = i - SA - SB - SC - SD;
      if (j < NG){ const int r=(j&3)*HH+(j>>2); b1p[j] = bih1[r] + bhh1[r]; }
      else if ((j -= NG) < NG){ const int r=(j&3)*HH+(j>>2); b2p[j] = bih2[r] + bhh2[r]; }
      else if ((j -= NG) < 32){ bswp[j] = (j < 30) ? bsw[j] : 0.f; }
      else { j -= 32; bmdp[j] = (j < MOUT) ? bmdn[j] : 0.f; }
    } else {
      const int j = i - SA - SB - SC - SD - SE;
      const int b = j >> 6, u = j & 63;
      const float* oh = onehots + (b*UU + u)*SENT;
      int c = 0;
#pragma unroll 1
      for (int q = 0; q < SENT; ++q) if (oh[q] > 0.5f) c = q;
      idx8[j] = (u8)c;
    }
  }
}

// ---------------- LDS layouts (per role) ----------------
struct G1S {
  float c[16*32];        // persistent cell state (this block's 16b x 32h slice)
  float kk[160];         // persistent kappa (16b x 10)
  u16   X1[16*584];      // staged A, stride 584 (pad 8 -> 2-way LDS aliasing only)
  float gates[16*132];
  float w[16*SENT];
  float p[16*32];
  float aa[160], bb[160];
  float phi[16*64];
};
struct G2S {
  float c[16*16];
  float kk[160];
  u16   X2[16*1096];
  float gates[16*68];
  float w[16*SENT];
  float p[16*32];
  float aa[160], bb[160];
  float phi[16*64];
};
struct MDS {
  u16   X[16*1032];
  float par[16*68];
};
union alignas(16) BigU { G1S g1; G2S g2; MDS md; };

// ---------------- per-batch-group epoch barrier ----------------
DEV void bg_barrier(u32* bar, int bg, int t){
  __syncthreads();                       // drains each wave's vmcnt before arrival
  if (threadIdx.x == 0){
    __threadfence();                     // agent-scope release of this block's stores
    u32* cnt = bar + bg*64;              // 256 B apart per group
    u32* flg = bar + bg*64 + 16;
    const u32 target = (u32)(t + 1);
    u32 old = __hip_atomic_fetch_add(cnt, 1u, __ATOMIC_ACQ_REL, __HIP_MEMORY_SCOPE_AGENT);
    if (old == target*(u32)BPG - 1u){
      __hip_atomic_store(flg, target, __ATOMIC_RELEASE, __HIP_MEMORY_SCOPE_AGENT);
    } else {
      while (__hip_atomic_load(flg, __ATOMIC_ACQUIRE, __HIP_MEMORY_SCOPE_AGENT) < target)
        __builtin_amdgcn_s_sleep(2);
    }
    __threadfence();                     // acquire side: invalidate stale caches
  }
  __syncthreads();
}

// ---------------- redundant attention: w[t-1] from h1[t-1] ----------------
DEV void compute_w(int t, int bg, const u16* __restrict__ h1prev,
                   float* w, float* p, float* aa, float* bb, float* kk, float* phi,
                   const float* __restrict__ wprev, const float* __restrict__ sm,
                   const u8* __restrict__ idx8, const u16* __restrict__ Wswp,
                   const float* __restrict__ bswp)
{
  const int tid = threadIdx.x;
  if (t == 0){
    for (int i = tid; i < 16*SENT; i += 256){
      int b = i / SENT, c = i - b*SENT;
      w[i] = wprev[(bg*16 + b)*SENT + c];
    }
    __syncthreads();
    return;
  }
  const int wave = tid >> 6, lane = tid & 63;
  if (wave < 2){   // p = h1 @ Wsw^T  (16 x 32, K=512), bf16 MFMA
    f32x4 acc = {0.f,0.f,0.f,0.f};
    const int n = wave*16 + (lane & 15);
    const u16* bp = Wswp + n*KSW + ((lane>>4)*8);
    const u16* ap = h1prev + (bg*16 + (lane&15))*HH + ((lane>>4)*8);
#pragma unroll
    for (int kt = 0; kt < KSW/32; ++kt)
      acc = mfma16(ld8(ap + kt*32), ld8(bp + kt*32), acc);
#pragma unroll
    for (int r = 0; r < 4; ++r)
      p[((lane>>4)*4 + r)*32 + n] = acc[r] + bswp[n];
  }
  __syncthreads();
  if (tid < 160){
    int b = tid/10, j = tid - b*10;
    aa[tid] = __expf(p[b*32 + j]);
    bb[tid] = __expf(p[b*32 + 10 + j]);
    kk[tid] += __expf(p[b*32 + 20 + j]);   // kappa accumulates (private copy)
  }
  for (int i = tid; i < 16*SENT; i += 256) w[i] = 0.f;
  __syncthreads();
  for (int i = tid; i < 16*UU; i += 256){
    const int b = i >> 6, u = i & 63;
    const float uf = (float)u;
    float acc = 0.f;
#pragma unroll
    for (int j = 0; j < KMIX; ++j){
      float d = kk[b*10 + j] - uf;
      acc = fmaf(aa[b*10 + j], __expf(-bb[b*10 + j]*d*d), acc);
    }
    phi[i] = acc * sm[(bg*16 + b)*UU + u];
  }
  __syncthreads();
  if (tid < 16){   // w[b][:] = scatter of phi via char indices
    const int b = tid;
    const u8* ib = idx8 + (bg*16 + b)*UU;
    float* wb = w + b*SENT;
    for (int u = 0; u < UU; ++u) wb[ib[u]] += phi[b*64 + u];
  }
  __syncthreads();
}

// ---------------- main persistent kernel ----------------
__global__ __launch_bounds__(256, 1) void rnn_main(
    const float* __restrict__ strks, const float* __restrict__ sm,
    const float* __restrict__ wprev, char* __restrict__ ws,
    float* __restrict__ out)
{
  u32* bar   = (u32*)(ws + OFF_BAR);
  u16* h1pub = (u16*)(ws + OFF_H1);
  u16* h2pub = (u16*)(ws + OFF_H2);
  const u8*  idx8 = (const u8*)(ws + OFF_IDX);
  const u16* Wp1  = (const u16*)(ws + OFF_W1);
  const u16* Wp2  = (const u16*)(ws + OFF_W2);
  const u16* Wswp = (const u16*)(ws + OFF_WSW);
  const u16* Wmdp = (const u16*)(ws + OFF_WMD);
  const float* b1p  = (const float*)(ws + OFF_B1);
  const float* b2p  = (const float*)(ws + OFF_B2);
  const float* bswp = (const float*)(ws + OFF_BSW);
  const float* bmdp = (const float*)(ws + OFF_BMD);

  __shared__ BigU S;

  const int bid = blockIdx.x, tid = threadIdx.x;
  const int wave = tid >> 6, lane = tid & 63;
  int role, bg, s;
  if (bid < NBG*G1B){ role = 0; bg = bid >> 4; s = bid & 15; }
  else if (bid < NBG*(G1B+G2B)){ const int b2 = bid - NBG*G1B; role = 1; bg = b2 >> 5; s = b2 & 31; }
  else { const int b2 = bid - NBG*(G1B+G2B); role = 2; bg = b2 >> 1; s = b2 & 1; }

  if (role == 0){
    for (int i = tid; i < 16*32; i += 256) S.g1.c[i] = 0.f;
    if (tid < 160) S.g1.kk[tid] = 0.f;
  } else if (role == 1){
    S.g2.c[tid & 255] = 0.f;
    if (tid < 160) S.g2.kk[tid] = 0.f;
  }
  __syncthreads();

  for (int t = 0; t < NITER; ++t){
    if (role == 0 && t < TT){
      // ---- LSTM1 step t: needs h1[t-1], w[t-1](recomputed) ----
      const u16* h1prev = h1pub + ((t+3)&3)*(BT*HH);
      compute_w(t, bg, h1prev, S.g1.w, S.g1.p, S.g1.aa, S.g1.bb, S.g1.kk, S.g1.phi,
                wprev, sm, idx8, Wswp, bswp);
      { // stage X1 (16 x 576): [h1][strk][w][pad]
        const int b = tid >> 4, l16 = tid & 15;
        u16x8* xr = (u16x8*)(S.g1.X1 + b*584);
        const u16x8* hr = (const u16x8*)(h1prev + (bg*16 + b)*HH);
#pragma unroll
        for (int jj = 0; jj < 4; ++jj) xr[l16 + 16*jj] = hr[l16 + 16*jj];
#pragma unroll
        for (int jj = 0; jj < 4; ++jj){
          const int k = 512 + l16 + 16*jj;
          u16 v;
          if (k < 515)      v = f2bf(strks[((bg*16 + b)*TT + t)*3 + (k-512)]);
          else if (k < 575) v = f2bf(S.g1.w[b*SENT + (k-515)]);
          else              v = 0;
          S.g1.X1[b*584 + k] = v;
        }
      }
      __syncthreads();
      f32x4 acc0 = {0.f,0.f,0.f,0.f}, acc1 = acc0;
      const int n0 = s*128 + wave*32 + (lane & 15);
      const int n1 = n0 + 16;
      const u16* bp0 = Wp1 + n0*K1P + ((lane>>4)*8);
      const u16* bp1 = Wp1 + n1*K1P + ((lane>>4)*8);
      const u16* ap  = S.g1.X1 + (lane&15)*584 + ((lane>>4)*8);
#pragma unroll
      for (int kt = 0; kt < K1P/32; ++kt){
        bf16x8 av = ld8(ap + kt*32);
        acc0 = mfma16(av, ld8(bp0 + kt*32), acc0);
        acc1 = mfma16(av, ld8(bp1 + kt*32), acc1);
      }
#pragma unroll
      for (int r = 0; r < 4; ++r){
        const int brow = (lane>>4)*4 + r;
        S.g1.gates[brow*132 + wave*32 + (lane&15)]      = acc0[r] + b1p[n0];
        S.g1.gates[brow*132 + wave*32 + 16 + (lane&15)] = acc1[r] + b1p[n1];
      }
      __syncthreads();
      u16* h1cur = h1pub + (t&3)*(BT*HH);
      for (int i = tid; i < 512; i += 256){
        const int b = i >> 5, j = i & 31;
        const float* gr = S.g1.gates + b*132 + 4*j;
        float c = sig_(gr[1])*S.g1.c[i] + sig_(gr[0])*tanh_(gr[2]);
        float h = sig_(gr[3])*tanh_(c);
        S.g1.c[i] = c;
        h1cur[(bg*16 + b)*HH + s*32 + j] = f2bf(h);
      }
    }
    else if (role == 1 && t >= 1 && t <= TT){
      // ---- LSTM2 step te=t-1: needs h1[te], w[te](recomputed), h2[te-1] ----
      const int te = t - 1;
      const u16* h1te = h1pub + (te&3)*(BT*HH);
      const u16* h2pv = h2pub + ((te+3)&3)*(BT*HH);
      compute_w(t, bg, h1te, S.g2.w, S.g2.p, S.g2.aa, S.g2.bb, S.g2.kk, S.g2.phi,
                wprev, sm, idx8, Wswp, bswp);
      { // stage X2 (16 x 1088): [h1][h2][strk][w][pad]
        const int b = tid >> 4, l16 = tid & 15;
        u16x8* xr = (u16x8*)(S.g2.X2 + b*1096);
        const u16x8* h1r = (const u16x8*)(h1te + (bg*16 + b)*HH);
        const u16x8* h2r = (const u16x8*)(h2pv + (bg*16 + b)*HH);
#pragma unroll
        for (int jj = 0; jj < 4; ++jj){
          xr[l16 + 16*jj]      = h1r[l16 + 16*jj];
          xr[64 + l16 + 16*jj] = h2r[l16 + 16*jj];
        }
#pragma unroll
        for (int jj = 0; jj < 4; ++jj){
          const int k = 1024 + l16 + 16*jj;
          u16 v;
          if (k < 1027)      v = f2bf(strks[((bg*16 + b)*TT + te)*3 + (k-1024)]);
          else if (k < 1087) v = f2bf(S.g2.w[b*SENT + (k-1027)]);
          else               v = 0;
          S.g2.X2[b*1096 + k] = v;
        }
      }
      __syncthreads();
      f32x4 acc = {0.f,0.f,0.f,0.f};
      const int n0 = s*64 + wave*16 + (lane & 15);
      const u16* bp = Wp2 + n0*K2P + ((lane>>4)*8);
      const u16* ap = S.g2.X2 + (lane&15)*1096 + ((lane>>4)*8);
#pragma unroll
      for (int kt = 0; kt < K2P/32; ++kt)
        acc = mfma16(ld8(ap + kt*32), ld8(bp + kt*32), acc);
#pragma unroll
      for (int r = 0; r < 4; ++r)
        S.g2.gates[((lane>>4)*4 + r)*68 + wave*16 + (lane&15)] = acc[r] + b2p[n0];
      __syncthreads();
      u16* h2cur = h2pub + (te&3)*(BT*HH);
      {
        const int b = tid >> 4, j = tid & 15;
        const float* gr = S.g2.gates + b*68 + 4*j;
        float c = sig_(gr[1])*S.g2.c[tid] + sig_(gr[0])*tanh_(gr[2]);
        float h = sig_(gr[3])*tanh_(c);
        S.g2.c[tid] = c;
        h2cur[(bg*16 + b)*HH + s*16 + j] = f2bf(h);
      }
    }
    else if (role == 2 && t >= 2){
      // ---- MDN head for step te=t-2: params = [h1;h2] @ Wmdn'^T + b ----
      const int te = t - 2;
      const u16* h1te = h1pub + (te&3)*(BT*HH);
      const u16* h2te = h2pub + (te&3)*(BT*HH);
      {
        const int b = tid >> 4, l16 = tid & 15;
        u16x8* xr = (u16x8*)(S.md.X + b*1032);
        const u16x8* h1r = (const u16x8*)(h1te + (bg*16 + b)*HH);
        const u16x8* h2r = (const u16x8*)(h2te + (bg*16 + b)*HH);
#pragma unroll
        for (int jj = 0; jj < 4; ++jj){
          xr[l16 + 16*jj]      = h1r[l16 + 16*jj];
          xr[64 + l16 + 16*jj] = h2r[l16 + 16*jj];
        }
      }
      __syncthreads();
      f32x4 acc = {0.f,0.f,0.f,0.f};
      const int n0 = s*64 + wave*16 + (lane & 15);
      const u16* bp = Wmdp + n0*KMD + ((lane>>4)*8);
      const u16* ap = S.md.X + (lane&15)*1032 + ((lane>>4)*8);
#pragma unroll
      for (int kt = 0; kt < KMD/32; ++kt)
        acc = mfma16(ld8(ap + kt*32), ld8(bp + kt*32), acc);
#pragma unroll
      for (int r = 0; r < 4; ++r)
        S.md.par[((lane>>4)*4 + r)*68 + wave*16 + (lane&15)] = acc[r] + bmdp[n0];
      __syncthreads();
      for (int i = tid; i < 1024; i += 256){
        const int b = i >> 6, lc = i & 63, gc = s*64 + lc;
        const int bt = (bg*16 + b)*TT + te;
        const float v = S.md.par[b*68 + lc];
        if (gc >= 20 && gc < 40)        out[OW_MU1 + bt*20 + (gc-20)]  = v;
        else if (gc >= 40 && gc < 60)   out[OW_MU2 + bt*20 + (gc-40)]  = v;
        else if (gc >= 60 && gc < 80)   out[OW_S1  + bt*20 + (gc-60)]  = __expf(v);
        else if (gc >= 80 && gc < 100)  out[OW_S2  + bt*20 + (gc-80)]  = __expf(v);
        else if (gc >= 100 && gc < 120) out[OW_RHO + bt*20 + (gc-100)] = tanh_(v);
        else if (gc == 120)             out[OW_EOS + bt]               = sig_(v);
      }
      if (s == 0 && tid < 16){   // softmax over pi (cols 0..19)
        const int b = tid;
        const int bt = (bg*16 + b)*TT + te;
        float mx = -1e30f;
        for (int c = 0; c < 20; ++c) mx = fmaxf(mx, S.md.par[b*68 + c]);
        float sum = 0.f;
        for (int c = 0; c < 20; ++c) sum += __expf(S.md.par[b*68 + c] - mx);
        const float inv = 1.f/sum;
        for (int c = 0; c < 20; ++c)
          out[OW_W + bt*20 + c] = __expf(S.md.par[b*68 + c] - mx)*inv;
      }
    }
    bg_barrier(bar, bg, t);
  }
}

extern "C" void kernel_launch(void* const* d_in, const int* in_sizes, int n_in,
                              void* d_out, int out_size, void* d_ws, size_t ws_size,
                              hipStream_t stream)
{
  const float* strks   = (const float*)d_in[0];
  // d_in[1] strks_m unused; d_in[2] sents unused (int64 ambiguity avoided via onehots)
  const float* sentsm  = (const float*)d_in[3];
  const float* onehots = (const float*)d_in[4];
  const float* wprev   = (const float*)d_in[5];
  const float* Wih1 = (const float*)d_in[6];
  const float* Whh1 = (const float*)d_in[7];
  const float* bih1 = (const float*)d_in[8];
  const float* bhh1 = (const float*)d_in[9];
  const float* Wih2 = (const float*)d_in[10];
  const float* Whh2 = (const float*)d_in[11];
  const float* bih2 = (const float*)d_in[12];
  const float* bhh2 = (const float*)d_in[13];
  const float* Wsw  = (const float*)d_in[14];
  const float* bsw  = (const float*)d_in[15];
  const float* Wmdn = (const float*)d_in[16];
  const float* bmdn = (const float*)d_in[17];
  (void)in_sizes; (void)n_in; (void)out_size;

  if (ws_size < (size_t)WS_NEED) return;  // fail loudly rather than corrupt

  hipMemsetAsync(d_ws, 0, ZERO_BYTES, stream);
  pack_kernel<<<2048, 256, 0, stream>>>(Wih1, Whh1, bih1, bhh1, Wih2, Whh2, bih2, bhh2,
                                        Wsw, bsw, Wmdn, bmdn, onehots, (char*)d_ws);
  rnn_main<<<NBLK, 256, 0, stream>>>(strks, sentsm, wprev, (char*)d_ws, (float*)d_out);
}

// Round 2
// 10201.508 us; speedup vs baseline: 2.2524x; 2.2524x over previous
//
#include <hip/hip_runtime.h>

// Handwriting synthesis RNN (Graves attention) — persistent fused kernel, R2.
// R2 changes vs R1: (1) all weight fragments live in per-lane VGPRs, loaded
// once before the time loop (removes 28 MB/iter L3 weight streaming that the
// barrier's cache invalidations made un-cacheable); (2) barrier polls with
// RELAXED device-scope atomics + one acquire fence (kills the buffer_inv
// storm); (3) attention w via precomputed u64 char-masks (removes 64-deep
// serial LDS scatter); (4) h1 staged into the GEMM tile first and reused by
// the attention MFMA; strks prefetched.

typedef unsigned short u16;
typedef unsigned int   u32;
typedef unsigned long long u64;
typedef u16   u16x8  __attribute__((ext_vector_type(8)));
typedef __bf16 bf16x8 __attribute__((ext_vector_type(8)));
typedef float f32x4  __attribute__((ext_vector_type(4)));

#define DEV static __device__ __forceinline__

// problem constants
#define BT   64
#define TT   800
#define UU   64
#define HH   512
#define SENT 60
#define NG   2048
#define MOUT 121
// packed K sizes
#define K1P 576    // X1 = [h1:512][strk:3][w:60][pad:1]
#define K2P 1088   // X2 = [h1:512][h2:512][strk:3][w:60][pad:1]
#define KMD 1024   // Xm = [h1:512][h2:512]
#define KSW 512

#define NBG 4
#define G1B 16     // gates1 blocks per bg (128 packed cols each)
#define G2B 32     // gates2 blocks per bg (64 packed cols each)
#define MDB 2      // mdn blocks per bg (64 cols each)
#define BPG (G1B + G2B + MDB)   // 50
#define NBLK (NBG * BPG)        // 200
#define NITER 802

// workspace layout (bytes)
#define OFF_BAR 0
#define OFF_H1  4096
#define OFF_H2  (OFF_H1 + 4*BT*HH*2)          // 266240
#define OFF_CM  (OFF_H2 + 4*BT*HH*2)          // 528384  (u64 masks, 64*60*8)
#define OFF_W1  (OFF_CM + 32768)              // 561152
#define OFF_W2  (OFF_W1 + NG*K1P*2)
#define OFF_WSW (OFF_W2 + NG*K2P*2)
#define OFF_WMD (OFF_WSW + 32*KSW*2)
#define OFF_B1  (OFF_WMD + 128*KMD*2)
#define OFF_B2  (OFF_B1 + NG*4)
#define OFF_BSW (OFF_B2 + NG*4)
#define OFF_BMD (OFF_BSW + 256)
#define WS_NEED (OFF_BMD + 512)
#define ZERO_BYTES OFF_CM   // barrier + h1/h2 rings

// output offsets (floats), reference return order
#define OW_EOS 0
#define OW_W   (BT*TT)
#define OW_MU1 (OW_W   + BT*TT*20)
#define OW_MU2 (OW_MU1 + BT*TT*20)
#define OW_S1  (OW_MU2 + BT*TT*20)
#define OW_S2  (OW_S1  + BT*TT*20)
#define OW_RHO (OW_S2  + BT*TT*20)

DEV u16 f2bf(float f){
  u32 u = __builtin_bit_cast(u32, f);
  u = (u + 0x7FFFu + ((u >> 16) & 1u)) >> 16;
  return (u16)u;
}
DEV bf16x8 ld8(const u16* p){ return __builtin_bit_cast(bf16x8, *(const u16x8*)p); }
DEV f32x4 mfma16(bf16x8 a, bf16x8 b, f32x4 c){
  return __builtin_amdgcn_mfma_f32_16x16x32_bf16(a, b, c, 0, 0, 0);
}
DEV float sig_(float x){ return 1.f/(1.f + __expf(-x)); }
DEV float tanh_(float x){
  float ax = fabsf(x);
  float e  = __expf(-2.f*ax);
  float t2 = (1.f - e)/(1.f + e);
  return x < 0.f ? -t2 : t2;
}

// ---------------- weight/bias/mask pre-pack ----------------
__global__ __launch_bounds__(256) void pack_kernel(
    const float* __restrict__ Wih1, const float* __restrict__ Whh1,
    const float* __restrict__ bih1, const float* __restrict__ bhh1,
    const float* __restrict__ Wih2, const float* __restrict__ Whh2,
    const float* __restrict__ bih2, const float* __restrict__ bhh2,
    const float* __restrict__ Wsw,  const float* __restrict__ bsw,
    const float* __restrict__ Wmdn, const float* __restrict__ bmdn,
    const float* __restrict__ onehots, char* __restrict__ ws)
{
  u16* Wp1  = (u16*)(ws + OFF_W1);
  u16* Wp2  = (u16*)(ws + OFF_W2);
  u16* Wswp = (u16*)(ws + OFF_WSW);
  u16* Wmdp = (u16*)(ws + OFF_WMD);
  float* b1p  = (float*)(ws + OFF_B1);
  float* b2p  = (float*)(ws + OFF_B2);
  float* bswp = (float*)(ws + OFF_BSW);
  float* bmdp = (float*)(ws + OFF_BMD);
  u64* cmask = (u64*)(ws + OFF_CM);

  const int SA = NG*K1P, SB = NG*K2P, SC = 32*KSW, SD = 128*KMD;
  const int SE = NG + NG + 32 + 128, SF = BT*SENT;
  const int total = SA+SB+SC+SD+SE+SF;
  for (int i = blockIdx.x*blockDim.x + threadIdx.x; i < total; i += gridDim.x*blockDim.x){
    if (i < SA){
      // packed gate col n = hdim*4 + gate ; original row r = gate*512 + hdim
      const int n = i / K1P, k = i - n*K1P;
      const int r = (n&3)*HH + (n>>2);
      float f;
      if (k < 512)      f = Whh1[r*HH + k];
      else if (k < 515) f = Wih1[r*63 + (k-512)];        // strks cols 0..2
      else if (k < 575) f = Wih1[r*63 + 3 + (k-515)];    // w cols 3..62
      else              f = 0.f;
      Wp1[i] = f2bf(f);
    } else if (i < SA+SB){
      const int j = i - SA;
      const int n = j / K2P, k = j - n*K2P;
      const int r = (n&3)*HH + (n>>2);
      float f;
      if (k < 512)       f = Wih2[r*575 + 3 + k];            // hid1
      else if (k < 1024) f = Whh2[r*HH + (k-512)];           // h2 recur
      else if (k < 1027) f = Wih2[r*575 + (k-1024)];         // strks
      else if (k < 1087) f = Wih2[r*575 + 515 + (k-1027)];   // win
      else               f = 0.f;
      Wp2[j] = f2bf(f);
    } else if (i < SA+SB+SC){
      const int j = i - SA - SB;
      const int n = j >> 9, k = j & 511;
      Wswp[j] = f2bf(n < 30 ? Wsw[n*KSW + k] : 0.f);
    } else if (i < SA+SB+SC+SD){
      const int j = i - SA - SB - SC;
      const int n = j >> 10, k = j & 1023;
      float f = 0.f;
      if (n < MOUT) f = (k < 512) ? Wmdn[n*1536 + k]
                                  : (Wmdn[n*1536 + 512 + (k-512)] + Wmdn[n*1536 + 1024 + (k-512)]);
      Wmdp[j] = f2bf(f);
    } else if (i < SA+SB+SC+SD+SE){
      int j = i - SA - SB - SC - SD;
      if (j < NG){ const int r=(j&3)*HH+(j>>2); b1p[j] = bih1[r] + bhh1[r]; }
      else if ((j -= NG) < NG){ const int r=(j&3)*HH+(j>>2); b2p[j] = bih2[r] + bhh2[r]; }
      else if ((j -= NG) < 32){ bswp[j] = (j < 30) ? bsw[j] : 0.f; }
      else { j -= 32; bmdp[j] = (j < MOUT) ? bmdn[j] : 0.f; }
    } else {
      const int j = i - SA - SB - SC - SD - SE;
      const int b = j / SENT, c = j - b*SENT;
      const float* oh = onehots + b*UU*SENT + c;
      u64 m = 0;
#pragma unroll 1
      for (int u = 0; u < UU; ++u) if (oh[u*SENT] > 0.5f) m |= (1ull << u);
      cmask[j] = m;
    }
  }
}

// ---------------- LDS layouts (per role) ----------------
struct G1S {
  float c[16*32];
  float kk[160];
  u16   X1[16*584];      // stride 584 u16 = 1168 B (16B aligned rows)
  float gates[16*132];
  float w[16*SENT];
  float pp[2][512];      // K-half partials of p (16x32)
  float aa[160], bb[160];
  float phi[16*64];
};
struct G2S {
  float c[16*16];
  float kk[160];
  u16   X2[16*1096];
  float gates[16*68];
  float w[16*SENT];
  float pp[2][512];
  float aa[160], bb[160];
  float phi[16*64];
};
struct MDS {
  u16   X[16*1032];
  float par[16*68];
};
union alignas(16) BigU { G1S g1; G2S g2; MDS md; };

// ---------------- per-batch-group epoch barrier ----------------
// Arrival RMW is ACQ_REL (its built-in wbl2/inv replaces explicit fences).
// Pollers spin RELAXED (device-scope sc bits give cross-XCD visibility
// WITHOUT per-poll buffer_inv), then one acquire fence.
DEV void bg_barrier(u32* bar, int bg, int t){
  __syncthreads();                       // drains vmcnt: stores are in L2
  if (threadIdx.x == 0){
    u32* cnt = bar + bg*64;              // 256 B apart per group
    u32* flg = bar + bg*64 + 32;         // 128 B from cnt
    const u32 target = (u32)(t + 1);
    u32 old = __hip_atomic_fetch_add(cnt, 1u, __ATOMIC_ACQ_REL, __HIP_MEMORY_SCOPE_AGENT);
    if (old == target*(u32)BPG - 1u){
      __hip_atomic_store(flg, target, __ATOMIC_RELEASE, __HIP_MEMORY_SCOPE_AGENT);
    } else {
      u32 v;
      do {
        __builtin_amdgcn_s_sleep(1);
        v = __hip_atomic_load(flg, __ATOMIC_RELAXED, __HIP_MEMORY_SCOPE_AGENT);
      } while (v < target);
      __builtin_amdgcn_fence(__ATOMIC_ACQUIRE, "agent");
    }
  }
  __syncthreads();
}

// ---------------- attention: w[..] from staged h1 (in LDS X tile) ----------
// Wsw fragments live in caller registers (wswr[8]): wave w covers col-tile
// (w&1) and K-half (w>>1); partials combined through pp[2][512].
DEV void compute_w(int t, int bg, const u16* __restrict__ X, int xstride,
                   float* w, float* pp, float* aa, float* bb, float* kk, float* phi,
                   const bf16x8* wswr, float bswa, float bswb, float bswk,
                   const float* __restrict__ wprev, const float* __restrict__ sm,
                   const u64* __restrict__ cmask)
{
  const int tid = threadIdx.x;
  if (t == 0){
    for (int i = tid; i < 16*SENT; i += 256){
      int b = i / SENT, c = i - b*SENT;
      w[i] = wprev[(bg*16 + b)*SENT + c];
    }
    __syncthreads();
    return;
  }
  const int wave = tid >> 6, lane = tid & 63;
  const int quad = lane >> 4, l15 = lane & 15;
  {   // partial p = h1 @ Wsw^T : wave (ct=w&1, kh=w>>1)
    f32x4 acc = {0.f,0.f,0.f,0.f};
    const u16* ap = X + l15*xstride + quad*8 + (wave>>1)*256;  // 8 kt of 32
#pragma unroll
    for (int j = 0; j < 8; ++j) acc = mfma16(ld8(ap + j*32), wswr[j], acc);
    const int n = (wave&1)*16 + l15;
    float* dst = pp + (wave>>1)*512;
#pragma unroll
    for (int r = 0; r < 4; ++r) dst[(quad*4 + r)*32 + n] = acc[r];
  }
  __syncthreads();
  if (tid < 160){
    const int b = tid/10, j = tid - b*10;
    const float pa = pp[b*32 + j]      + pp[512 + b*32 + j]      + bswa;
    const float pb = pp[b*32 + 10 + j] + pp[512 + b*32 + 10 + j] + bswb;
    const float pk = pp[b*32 + 20 + j] + pp[512 + b*32 + 20 + j] + bswk;
    aa[tid] = __expf(pa);
    bb[tid] = __expf(pb);
    kk[tid] += __expf(pk);   // kappa accumulates (private per-block copy)
  }
  __syncthreads();
  for (int i = tid; i < 16*UU; i += 256){
    const int b = i >> 6, u = i & 63;
    const float uf = (float)u;
    float acc = 0.f;
#pragma unroll
    for (int j = 0; j < 10; ++j){
      float d = kk[b*10 + j] - uf;
      acc = fmaf(aa[b*10 + j], __expf(-bb[b*10 + j]*d*d), acc);
    }
    phi[i] = acc * sm[(bg*16 + b)*UU + u];
  }
  __syncthreads();
  for (int i = tid; i < 16*SENT; i += 256){
    const int b = i / SENT, c = i - b*SENT;
    u64 m = cmask[(bg*16 + b)*SENT + c];
    float acc = 0.f;
    while (m){ const int u = __builtin_ctzll(m); m &= m - 1; acc += phi[b*64 + u]; }
    w[i] = acc;
  }
  __syncthreads();
}

// ---------------- main persistent kernel ----------------
__global__ __launch_bounds__(256, 1) void rnn_main(
    const float* __restrict__ strks, const float* __restrict__ sm,
    const float* __restrict__ wprev, char* __restrict__ ws,
    float* __restrict__ out)
{
  u32* bar   = (u32*)(ws + OFF_BAR);
  u16* h1pub = (u16*)(ws + OFF_H1);
  u16* h2pub = (u16*)(ws + OFF_H2);
  const u64* cmask = (const u64*)(ws + OFF_CM);
  const u16* Wp1  = (const u16*)(ws + OFF_W1);
  const u16* Wp2  = (const u16*)(ws + OFF_W2);
  const u16* Wswp = (const u16*)(ws + OFF_WSW);
  const u16* Wmdp = (const u16*)(ws + OFF_WMD);
  const float* b1p  = (const float*)(ws + OFF_B1);
  const float* b2p  = (const float*)(ws + OFF_B2);
  const float* bswp = (const float*)(ws + OFF_BSW);
  const float* bmdp = (const float*)(ws + OFF_BMD);

  __shared__ BigU S;

  const int bid = blockIdx.x, tid = threadIdx.x;
  const int wave = tid >> 6, lane = tid & 63;
  const int quad = lane >> 4, l15 = lane & 15;
  const int sb = tid >> 4, sl = tid & 15;     // staging coords

  if (bid < NBG*G1B){
    // ================= role 0: LSTM1 (step t) =================
    const int bg = bid >> 4, s = bid & 15;
    bf16x8 w1r[36];
    const int n0 = s*128 + wave*32 + l15, n1 = n0 + 16;
#pragma unroll
    for (int kt = 0; kt < 18; ++kt){
      w1r[2*kt]   = ld8(Wp1 + n0*K1P + quad*8 + kt*32);
      w1r[2*kt+1] = ld8(Wp1 + n1*K1P + quad*8 + kt*32);
    }
    bf16x8 wswr[8];
    { const int nsw = (wave&1)*16 + l15, k0 = (wave>>1)*8;
#pragma unroll
      for (int j = 0; j < 8; ++j) wswr[j] = ld8(Wswp + nsw*KSW + quad*8 + (k0+j)*32);
    }
    const float bias0 = b1p[n0], bias1 = b1p[n1];
    float bswa = 0.f, bswb = 0.f, bswk = 0.f;
    if (tid < 160){ const int j = tid % 10; bswa = bswp[j]; bswb = bswp[10+j]; bswk = bswp[20+j]; }
    for (int i = tid; i < 512; i += 256) S.g1.c[i] = 0.f;
    if (tid < 160) S.g1.kk[tid] = 0.f;
    __syncthreads();

    for (int t = 0; t < NITER; ++t){
      if (t < TT){
        const u16* h1prev = h1pub + ((t+3)&3)*(BT*HH);
        float sv = 0.f;
        if (sl < 3) sv = strks[((bg*16 + sb)*TT + t)*3 + sl];   // prefetch
        { // stage h1[t-1] into X1 rows (also the attention A operand)
          u16x8* xr = (u16x8*)(S.g1.X1 + sb*584);
          const u16x8* hr = (const u16x8*)(h1prev + (bg*16 + sb)*HH);
#pragma unroll
          for (int jj = 0; jj < 4; ++jj) xr[sl + 16*jj] = hr[sl + 16*jj];
        }
        __syncthreads();
        compute_w(t, bg, S.g1.X1, 584, S.g1.w, &S.g1.pp[0][0], S.g1.aa, S.g1.bb,
                  S.g1.kk, S.g1.phi, wswr, bswa, bswb, bswk, wprev, sm, cmask);
        { // X1 tail: [strk:3][w:60][pad]
#pragma unroll
          for (int jj = 0; jj < 4; ++jj){
            const int k = 512 + sl + 16*jj;
            u16 v;
            if (k < 515)      v = f2bf(sv);
            else if (k < 575) v = f2bf(S.g1.w[sb*SENT + (k-515)]);
            else              v = 0;
            S.g1.X1[sb*584 + k] = v;
          }
        }
        __syncthreads();
        f32x4 acc0 = {0.f,0.f,0.f,0.f}, acc1 = {0.f,0.f,0.f,0.f};
        const u16* ap = S.g1.X1 + l15*584 + quad*8;
#pragma unroll
        for (int kt = 0; kt < 18; ++kt){
          bf16x8 av = ld8(ap + kt*32);
          acc0 = mfma16(av, w1r[2*kt],   acc0);
          acc1 = mfma16(av, w1r[2*kt+1], acc1);
        }
#pragma unroll
        for (int r = 0; r < 4; ++r){
          const int brow = quad*4 + r;
          S.g1.gates[brow*132 + wave*32 + l15]      = acc0[r] + bias0;
          S.g1.gates[brow*132 + wave*32 + 16 + l15] = acc1[r] + bias1;
        }
        __syncthreads();
        u16* h1cur = h1pub + (t&3)*(BT*HH);
        for (int i = tid; i < 512; i += 256){
          const int b = i >> 5, j = i & 31;
          const float* gr = S.g1.gates + b*132 + 4*j;
          float c = sig_(gr[1])*S.g1.c[i] + sig_(gr[0])*tanh_(gr[2]);
          S.g1.c[i] = c;
          h1cur[(bg*16 + b)*HH + s*32 + j] = f2bf(sig_(gr[3])*tanh_(c));
        }
      }
      bg_barrier(bar, bg, t);
    }
  }
  else if (bid < NBG*(G1B+G2B)){
    // ================= role 1: LSTM2 (step te = t-1) =================
    const int b2 = bid - NBG*G1B, bg = b2 >> 5, s = b2 & 31;
    bf16x8 w2r[34];
    const int n0 = s*64 + wave*16 + l15;
#pragma unroll
    for (int kt = 0; kt < 34; ++kt) w2r[kt] = ld8(Wp2 + n0*K2P + quad*8 + kt*32);
    bf16x8 wswr[8];
    { const int nsw = (wave&1)*16 + l15, k0 = (wave>>1)*8;
#pragma unroll
      for (int j = 0; j < 8; ++j) wswr[j] = ld8(Wswp + nsw*KSW + quad*8 + (k0+j)*32);
    }
    const float bias0 = b2p[n0];
    float bswa = 0.f, bswb = 0.f, bswk = 0.f;
    if (tid < 160){ const int j = tid % 10; bswa = bswp[j]; bswb = bswp[10+j]; bswk = bswp[20+j]; }
    S.g2.c[tid] = 0.f;
    if (tid < 160) S.g2.kk[tid] = 0.f;
    __syncthreads();

    for (int t = 0; t < NITER; ++t){
      if (t >= 1 && t <= TT){
        const int te = t - 1;
        const u16* h1te = h1pub + (te&3)*(BT*HH);
        const u16* h2pv = h2pub + ((te+3)&3)*(BT*HH);
        float sv = 0.f;
        if (sl < 3) sv = strks[((bg*16 + sb)*TT + te)*3 + sl];
        { // stage [h1te | h2prev] into X2
          u16x8* xr = (u16x8*)(S.g2.X2 + sb*1096);
          const u16x8* h1r = (const u16x8*)(h1te + (bg*16 + sb)*HH);
          const u16x8* h2r = (const u16x8*)(h2pv + (bg*16 + sb)*HH);
#pragma unroll
          for (int jj = 0; jj < 4; ++jj){
            xr[sl + 16*jj]      = h1r[sl + 16*jj];
            xr[64 + sl + 16*jj] = h2r[sl + 16*jj];
          }
        }
        __syncthreads();
        compute_w(t, bg, S.g2.X2, 1096, S.g2.w, &S.g2.pp[0][0], S.g2.aa, S.g2.bb,
                  S.g2.kk, S.g2.phi, wswr, bswa, bswb, bswk, wprev, sm, cmask);
        { // X2 tail
#pragma unroll
          for (int jj = 0; jj < 4; ++jj){
            const int k = 1024 + sl + 16*jj;
            u16 v;
            if (k < 1027)      v = f2bf(sv);
            else if (k < 1087) v = f2bf(S.g2.w[sb*SENT + (k-1027)]);
            else               v = 0;
            S.g2.X2[sb*1096 + k] = v;
          }
        }
        __syncthreads();
        f32x4 acc = {0.f,0.f,0.f,0.f};
        const u16* ap = S.g2.X2 + l15*1096 + quad*8;
#pragma unroll
        for (int kt = 0; kt < 34; ++kt) acc = mfma16(ld8(ap + kt*32), w2r[kt], acc);
#pragma unroll
        for (int r = 0; r < 4; ++r)
          S.g2.gates[(quad*4 + r)*68 + wave*16 + l15] = acc[r] + bias0;
        __syncthreads();
        u16* h2cur = h2pub + (te&3)*(BT*HH);
        {
          const int b = tid >> 4, j = tid & 15;
          const float* gr = S.g2.gates + b*68 + 4*j;
          float c = sig_(gr[1])*S.g2.c[tid] + sig_(gr[0])*tanh_(gr[2]);
          S.g2.c[tid] = c;
          h2cur[(bg*16 + b)*HH + s*16 + j] = f2bf(sig_(gr[3])*tanh_(c));
        }
      }
      bg_barrier(bar, bg, t);
    }
  }
  else {
    // ================= role 2: MDN head (step te = t-2) =================
    const int b2 = bid - NBG*(G1B+G2B), bg = b2 >> 1, s = b2 & 1;
    bf16x8 wmr[32];
    const int n0 = s*64 + wave*16 + l15;
#pragma unroll
    for (int kt = 0; kt < 32; ++kt) wmr[kt] = ld8(Wmdp + n0*KMD + quad*8 + kt*32);
    const float bias0 = bmdp[n0];
    __syncthreads();

    for (int t = 0; t < NITER; ++t){
      if (t >= 2){
        const int te = t - 2;
        const u16* h1te = h1pub + (te&3)*(BT*HH);
        const u16* h2te = h2pub + (te&3)*(BT*HH);
        {
          u16x8* xr = (u16x8*)(S.md.X + sb*1032);
          const u16x8* h1r = (const u16x8*)(h1te + (bg*16 + sb)*HH);
          const u16x8* h2r = (const u16x8*)(h2te + (bg*16 + sb)*HH);
#pragma unroll
          for (int jj = 0; jj < 4; ++jj){
            xr[sl + 16*jj]      = h1r[sl + 16*jj];
            xr[64 + sl + 16*jj] = h2r[sl + 16*jj];
          }
        }
        __syncthreads();
        f32x4 acc = {0.f,0.f,0.f,0.f};
        const u16* ap = S.md.X + l15*1032 + quad*8;
#pragma unroll
        for (int kt = 0; kt < 32; ++kt) acc = mfma16(ld8(ap + kt*32), wmr[kt], acc);
#pragma unroll
        for (int r = 0; r < 4; ++r)
          S.md.par[(quad*4 + r)*68 + wave*16 + l15] = acc[r] + bias0;
        __syncthreads();
        for (int i = tid; i < 1024; i += 256){
          const int b = i >> 6, lc = i & 63, gc = s*64 + lc;
          const int bt = (bg*16 + b)*TT + te;
          const float v = S.md.par[b*68 + lc];
          if (gc >= 20 && gc < 40)        out[OW_MU1 + bt*20 + (gc-20)]  = v;
          else if (gc >= 40 && gc < 60)   out[OW_MU2 + bt*20 + (gc-40)]  = v;
          else if (gc >= 60 && gc < 80)   out[OW_S1  + bt*20 + (gc-60)]  = __expf(v);
          else if (gc >= 80 && gc < 100)  out[OW_S2  + bt*20 + (gc-80)]  = __expf(v);
          else if (gc >= 100 && gc < 120) out[OW_RHO + bt*20 + (gc-100)] = tanh_(v);
          else if (gc == 120)             out[OW_EOS + bt]               = sig_(v);
        }
        if (s == 0 && tid < 16){   // softmax over pi (cols 0..19)
          const int b = tid;
          const int bt = (bg*16 + b)*TT + te;
          float mx = -1e30f;
          for (int c = 0; c < 20; ++c) mx = fmaxf(mx, S.md.par[b*68 + c]);
          float sum = 0.f;
          for (int c = 0; c < 20; ++c) sum += __expf(S.md.par[b*68 + c] - mx);
          const float inv = 1.f/sum;
          for (int c = 0; c < 20; ++c)
            out[OW_W + bt*20 + c] = __expf(S.md.par[b*68 + c] - mx)*inv;
        }
      }
      bg_barrier(bar, bg, t);
    }
  }
}

extern "C" void kernel_launch(void* const* d_in, const int* in_sizes, int n_in,
                              void* d_out, int out_size, void* d_ws, size_t ws_size,
                              hipStream_t stream)
{
  const float* strks   = (const float*)d_in[0];
  const float* sentsm  = (const float*)d_in[3];
  const float* onehots = (const float*)d_in[4];
  const float* wprev   = (const float*)d_in[5];
  const float* Wih1 = (const float*)d_in[6];
  const float* Whh1 = (const float*)d_in[7];
  const float* bih1 = (const float*)d_in[8];
  const float* bhh1 = (const float*)d_in[9];
  const float* Wih2 = (const float*)d_in[10];
  const float* Whh2 = (const float*)d_in[11];
  const float* bih2 = (const float*)d_in[12];
  const float* bhh2 = (const float*)d_in[13];
  const float* Wsw  = (const float*)d_in[14];
  const float* bsw  = (const float*)d_in[15];
  const float* Wmdn = (const float*)d_in[16];
  const float* bmdn = (const float*)d_in[17];
  (void)in_sizes; (void)n_in; (void)out_size;

  if (ws_size < (size_t)WS_NEED) return;

  hipMemsetAsync(d_ws, 0, ZERO_BYTES, stream);
  pack_kernel<<<2048, 256, 0, stream>>>(Wih1, Whh1, bih1, bhh1, Wih2, Whh2, bih2, bhh2,
                                        Wsw, bsw, Wmdn, bmdn, onehots, (char*)d_ws);
  rnn_main<<<NBLK, 256, 0, stream>>>(strks, sentsm, wprev, (char*)d_ws, (float*)d_out);
}

// Round 3
// 5483.461 us; speedup vs baseline: 4.1904x; 1.8604x over previous
//
#include <hip/hip_runtime.h>

// Handwriting synthesis RNN — persistent fused kernel, R3.
// R3 vs R2: zero cache-maintenance in the steady loop. Ring traffic goes
// through L3 explicitly (sc0 sc1 loads/stores), atomics are RELAXED
// fire-and-forget counters, roles decoupled (role0's critical path = its own
// 16-block group), constants LDS-resident, Wsw frags passed by value,
// attention writes w directly into the GEMM tile tail.

typedef unsigned short u16;
typedef unsigned int   u32;
typedef unsigned long long u64;
typedef u16   u16x8  __attribute__((ext_vector_type(8)));
typedef __bf16 bf16x8 __attribute__((ext_vector_type(8)));
typedef float f32x4  __attribute__((ext_vector_type(4)));

#define DEV static __device__ __forceinline__

// problem constants
#define BT   64
#define TT   800
#define UU   64
#define HH   512
#define SENT 60
#define NG   2048
#define MOUT 121
#define K1P 576    // X1 = [h1:512][strk:3][w:60][pad:1]
#define K2P 1088   // X2 = [h1:512][h2:512][strk:3][w:60][pad:1]
#define KMD 1024   // Xm = [h1:512][h2:512]
#define KSW 512

#define NBG 4
#define G1B 16
#define G2B 32
#define MDB 2
#define NBLK (NBG*(G1B+G2B+MDB))   // 200

// workspace layout (bytes)
#define OFF_BAR 0
#define OFF_H1  4096
#define OFF_H2  (OFF_H1 + 4*BT*HH*2)
#define OFF_CM  (OFF_H2 + 4*BT*HH*2)
#define OFF_W1  (OFF_CM + 32768)
#define OFF_W2  (OFF_W1 + NG*K1P*2)
#define OFF_WSW (OFF_W2 + NG*K2P*2)
#define OFF_WMD (OFF_WSW + 32*KSW*2)
#define OFF_B1  (OFF_WMD + 128*KMD*2)
#define OFF_B2  (OFF_B1 + NG*4)
#define OFF_BSW (OFF_B2 + NG*4)
#define OFF_BMD (OFF_BSW + 256)
#define WS_NEED (OFF_BMD + 512)
#define ZERO_BYTES OFF_CM   // counters + h1/h2 rings

// output offsets (floats)
#define OW_EOS 0
#define OW_W   (BT*TT)
#define OW_MU1 (OW_W   + BT*TT*20)
#define OW_MU2 (OW_MU1 + BT*TT*20)
#define OW_S1  (OW_MU2 + BT*TT*20)
#define OW_S2  (OW_S1  + BT*TT*20)
#define OW_RHO (OW_S2  + BT*TT*20)

DEV u16 f2bf(float f){
  u32 u = __builtin_bit_cast(u32, f);
  u = (u + 0x7FFFu + ((u >> 16) & 1u)) >> 16;
  return (u16)u;
}
DEV bf16x8 ld8(const u16* p){ return __builtin_bit_cast(bf16x8, *(const u16x8*)p); }
DEV f32x4 mfma16(bf16x8 a, bf16x8 b, f32x4 c){
  return __builtin_amdgcn_mfma_f32_16x16x32_bf16(a, b, c, 0, 0, 0);
}
DEV float sig_(float x){ return 1.f/(1.f + __expf(-x)); }
DEV float tanh_(float x){
  float ax = fabsf(x);
  float e  = __expf(-2.f*ax);
  float t2 = (1.f - e)/(1.f + e);
  return x < 0.f ? -t2 : t2;
}

// ---- L3-coherent (device-scope) memory helpers: no wbl2/inv anywhere ----
DEV void ld_tile4(const u16* p, u16x8& a0, u16x8& a1, u16x8& a2, u16x8& a3){
  asm volatile(
    "global_load_dwordx4 %0, %4, off sc0 sc1\n\t"
    "global_load_dwordx4 %1, %4, off offset:256 sc0 sc1\n\t"
    "global_load_dwordx4 %2, %4, off offset:512 sc0 sc1\n\t"
    "global_load_dwordx4 %3, %4, off offset:768 sc0 sc1\n\t"
    "s_waitcnt vmcnt(0)"
    : "=&v"(a0), "=&v"(a1), "=&v"(a2), "=&v"(a3)
    : "v"(p) : "memory");
}
DEV void ld_tile8(const u16* p1, const u16* p2,
                  u16x8& a0,u16x8& a1,u16x8& a2,u16x8& a3,
                  u16x8& b0,u16x8& b1,u16x8& b2,u16x8& b3){
  asm volatile(
    "global_load_dwordx4 %0, %8, off sc0 sc1\n\t"
    "global_load_dwordx4 %1, %8, off offset:256 sc0 sc1\n\t"
    "global_load_dwordx4 %2, %8, off offset:512 sc0 sc1\n\t"
    "global_load_dwordx4 %3, %8, off offset:768 sc0 sc1\n\t"
    "global_load_dwordx4 %4, %9, off sc0 sc1\n\t"
    "global_load_dwordx4 %5, %9, off offset:256 sc0 sc1\n\t"
    "global_load_dwordx4 %6, %9, off offset:512 sc0 sc1\n\t"
    "global_load_dwordx4 %7, %9, off offset:768 sc0 sc1\n\t"
    "s_waitcnt vmcnt(0)"
    : "=&v"(a0),"=&v"(a1),"=&v"(a2),"=&v"(a3),
      "=&v"(b0),"=&v"(b1),"=&v"(b2),"=&v"(b3)
    : "v"(p1), "v"(p2) : "memory");
}
DEV void st_short_sc(u16* p, u32 v){
  asm volatile("global_store_short %0, %1, off sc0 sc1" :: "v"(p), "v"(v) : "memory");
}
DEV void vmwait0(){ asm volatile("s_waitcnt vmcnt(0)" ::: "memory"); }

DEV void wait3(const u32* p0, int t0, const u32* p1, int t1, const u32* p2, int t2){
  if (t0 <= 0 && t1 <= 0 && t2 <= 0) return;
  for(;;){
    u32 a, b, c;
    asm volatile(
      "global_load_dword %0, %3, off sc0 sc1\n\t"
      "global_load_dword %1, %4, off sc0 sc1\n\t"
      "global_load_dword %2, %5, off sc0 sc1\n\t"
      "s_waitcnt vmcnt(0)"
      : "=&v"(a), "=&v"(b), "=&v"(c)
      : "v"(p0), "v"(p1), "v"(p2) : "memory");
    if ((int)a >= t0 && (int)b >= t1 && (int)c >= t2) return;
    __builtin_amdgcn_s_sleep(1);
  }
}
DEV void wait1(const u32* p0, int t0){
  if (t0 <= 0) return;
  for(;;){
    u32 a;
    asm volatile("global_load_dword %0, %1, off sc0 sc1\n\ts_waitcnt vmcnt(0)"
      : "=&v"(a) : "v"(p0) : "memory");
    if ((int)a >= t0) return;
    __builtin_amdgcn_s_sleep(1);
  }
}
DEV void arrive(u32* cnt){
  __hip_atomic_fetch_add(cnt, 1u, __ATOMIC_RELAXED, __HIP_MEMORY_SCOPE_AGENT);
}

// ---------------- weight/bias/mask pre-pack (unchanged from R2) ----------
__global__ __launch_bounds__(256) void pack_kernel(
    const float* __restrict__ Wih1, const float* __restrict__ Whh1,
    const float* __restrict__ bih1, const float* __restrict__ bhh1,
    const float* __restrict__ Wih2, const float* __restrict__ Whh2,
    const float* __restrict__ bih2, const float* __restrict__ bhh2,
    const float* __restrict__ Wsw,  const float* __restrict__ bsw,
    const float* __restrict__ Wmdn, const float* __restrict__ bmdn,
    const float* __restrict__ onehots, char* __restrict__ ws)
{
  u16* Wp1  = (u16*)(ws + OFF_W1);
  u16* Wp2  = (u16*)(ws + OFF_W2);
  u16* Wswp = (u16*)(ws + OFF_WSW);
  u16* Wmdp = (u16*)(ws + OFF_WMD);
  float* b1p  = (float*)(ws + OFF_B1);
  float* b2p  = (float*)(ws + OFF_B2);
  float* bswp = (float*)(ws + OFF_BSW);
  float* bmdp = (float*)(ws + OFF_BMD);
  u64* cmask = (u64*)(ws + OFF_CM);

  const int SA = NG*K1P, SB = NG*K2P, SC = 32*KSW, SD = 128*KMD;
  const int SE = NG + NG + 32 + 128, SF = BT*SENT;
  const int total = SA+SB+SC+SD+SE+SF;
  for (int i = blockIdx.x*blockDim.x + threadIdx.x; i < total; i += gridDim.x*blockDim.x){
    if (i < SA){
      const int n = i / K1P, k = i - n*K1P;
      const int r = (n&3)*HH + (n>>2);
      float f;
      if (k < 512)      f = Whh1[r*HH + k];
      else if (k < 515) f = Wih1[r*63 + (k-512)];
      else if (k < 575) f = Wih1[r*63 + 3 + (k-515)];
      else              f = 0.f;
      Wp1[i] = f2bf(f);
    } else if (i < SA+SB){
      const int j = i - SA;
      const int n = j / K2P, k = j - n*K2P;
      const int r = (n&3)*HH + (n>>2);
      float f;
      if (k < 512)       f = Wih2[r*575 + 3 + k];
      else if (k < 1024) f = Whh2[r*HH + (k-512)];
      else if (k < 1027) f = Wih2[r*575 + (k-1024)];
      else if (k < 1087) f = Wih2[r*575 + 515 + (k-1027)];
      else               f = 0.f;
      Wp2[j] = f2bf(f);
    } else if (i < SA+SB+SC){
      const int j = i - SA - SB;
      const int n = j >> 9, k = j & 511;
      Wswp[j] = f2bf(n < 30 ? Wsw[n*KSW + k] : 0.f);
    } else if (i < SA+SB+SC+SD){
      const int j = i - SA - SB - SC;
      const int n = j >> 10, k = j & 1023;
      float f = 0.f;
      if (n < MOUT) f = (k < 512) ? Wmdn[n*1536 + k]
                                  : (Wmdn[n*1536 + 512 + (k-512)] + Wmdn[n*1536 + 1024 + (k-512)]);
      Wmdp[j] = f2bf(f);
    } else if (i < SA+SB+SC+SD+SE){
      int j = i - SA - SB - SC - SD;
      if (j < NG){ const int r=(j&3)*HH+(j>>2); b1p[j] = bih1[r] + bhh1[r]; }
      else if ((j -= NG) < NG){ const int r=(j&3)*HH+(j>>2); b2p[j] = bih2[r] + bhh2[r]; }
      else if ((j -= NG) < 32){ bswp[j] = (j < 30) ? bsw[j] : 0.f; }
      else { j -= 32; bmdp[j] = (j < MOUT) ? bmdn[j] : 0.f; }
    } else {
      const int j = i - SA - SB - SC - SD - SE;
      const int b = j / SENT, c = j - b*SENT;
      const float* oh = onehots + b*UU*SENT + c;
      u64 m = 0;
#pragma unroll 1
      for (int u = 0; u < UU; ++u) if (oh[u*SENT] > 0.5f) m |= (1ull << u);
      cmask[j] = m;
    }
  }
}

// ---------------- LDS layouts ----------------
struct G1S {
  float c[512]; float kk[160];
  u16   X1[16*584];
  float gates[16*132];
  float pp[1024]; float aa[160], bb[160];
  float phi[1024]; float smv[1024];
  u64   cm[960];
};
struct G2S {
  float c[256]; float kk[160];
  u16   X2[16*1096];
  float gates[16*68];
  float pp[1024]; float aa[160], bb[160];
  float phi[1024]; float smv[1024];
  u64   cm[960];
};
struct MDS { u16 X[16*1032]; float par[16*68]; };
union alignas(16) BigU { G1S g1; G2S g2; MDS md; };

struct WswF { bf16x8 f[8]; };   // by-value => stays in VGPRs after inlining

// attention for step (tw-1): p = h1 @ Wsw^T from staged X (cols 0..511),
// kappa accumulates in kk (private per-block), writes bf16 w directly into
// the X tile tail at tailoff. tw==0 => copy wprev into tail.
DEV void attn_tail(int tw, int bg, u16* X, int xstride, int tailoff,
                   float* pp, float* aa, float* bb, float* kk, float* phi,
                   const float* smv, const u64* cmL, WswF wf,
                   float bswa, float bswb, float bswk,
                   const float* __restrict__ wprev)
{
  const int tid = threadIdx.x;
  if (tw == 0){
    for (int i = tid; i < 16*SENT; i += 256){
      const int b = i / SENT, c = i - b*SENT;
      X[b*xstride + tailoff + c] = f2bf(wprev[(bg*16 + b)*SENT + c]);
    }
    return;
  }
  const int wave = tid >> 6, lane = tid & 63;
  const int quad = lane >> 4, l15 = lane & 15;
  {
    f32x4 acc = {0.f,0.f,0.f,0.f};
    const u16* ap = X + l15*xstride + quad*8 + (wave>>1)*256;
#pragma unroll
    for (int j = 0; j < 8; ++j) acc = mfma16(ld8(ap + j*32), wf.f[j], acc);
    float* dst = pp + (wave>>1)*512;
    const int n = (wave&1)*16 + l15;
#pragma unroll
    for (int r = 0; r < 4; ++r) dst[(quad*4 + r)*32 + n] = acc[r];
  }
  __syncthreads();
  if (tid < 160){
    const int b = tid/10, j = tid - b*10;
    aa[tid] = __expf(pp[b*32 + j]      + pp[512 + b*32 + j]      + bswa);
    bb[tid] = __expf(pp[b*32 + 10 + j] + pp[512 + b*32 + 10 + j] + bswb);
    kk[tid] += __expf(pp[b*32 + 20 + j] + pp[512 + b*32 + 20 + j] + bswk);
  }
  __syncthreads();
  for (int i = tid; i < 1024; i += 256){
    const int b = i >> 6, u = i & 63;
    const float uf = (float)u;
    float acc = 0.f;
#pragma unroll
    for (int j = 0; j < 10; ++j){
      float d = kk[b*10 + j] - uf;
      acc = fmaf(aa[b*10 + j], __expf(-bb[b*10 + j]*d*d), acc);
    }
    phi[i] = acc * smv[i];
  }
  __syncthreads();
  for (int i = tid; i < 16*SENT; i += 256){
    const int b = i / SENT, c = i - b*SENT;
    u64 m = cmL[i];
    float acc = 0.f;
    while (m){ const int u = __builtin_ctzll(m); m &= m - 1; acc += phi[b*64 + u]; }
    X[b*xstride + tailoff + c] = f2bf(acc);
  }
}

// ---------------- main persistent kernel ----------------
__global__ __launch_bounds__(256, 1) void rnn_main(
    const float* __restrict__ strks, const float* __restrict__ sm,
    const float* __restrict__ wprev, char* __restrict__ ws,
    float* __restrict__ out)
{
  u32* bar   = (u32*)(ws + OFF_BAR);
  u16* h1pub = (u16*)(ws + OFF_H1);
  u16* h2pub = (u16*)(ws + OFF_H2);
  const u64* cmask = (const u64*)(ws + OFF_CM);
  const u16* Wp1  = (const u16*)(ws + OFF_W1);
  const u16* Wp2  = (const u16*)(ws + OFF_W2);
  const u16* Wswp = (const u16*)(ws + OFF_WSW);
  const u16* Wmdp = (const u16*)(ws + OFF_WMD);
  const float* b1p  = (const float*)(ws + OFF_B1);
  const float* b2p  = (const float*)(ws + OFF_B2);
  const float* bswp = (const float*)(ws + OFF_BSW);
  const float* bmdp = (const float*)(ws + OFF_BMD);

  __shared__ BigU S;

  const int bid = blockIdx.x, tid = threadIdx.x;
  const int wave = tid >> 6, lane = tid & 63;
  const int quad = lane >> 4, l15 = lane & 15;
  const int sb = tid >> 4, sl = tid & 15;

  if (bid < NBG*G1B){
    // ============ role 0: LSTM1 step t; own 16-block group ============
    const int bg = bid >> 4, s = bid & 15;
    u32* cnt0 = bar + bg*192;
    u32* cnt1 = bar + bg*192 + 64;
    u32* cnt2 = bar + bg*192 + 128;
    bf16x8 w1r[36];
    const int n0 = s*128 + wave*32 + l15, n1 = n0 + 16;
#pragma unroll
    for (int kt = 0; kt < 18; ++kt){
      w1r[2*kt]   = ld8(Wp1 + n0*K1P + quad*8 + kt*32);
      w1r[2*kt+1] = ld8(Wp1 + n1*K1P + quad*8 + kt*32);
    }
    WswF wf;
    { const int nsw = (wave&1)*16 + l15, k0 = (wave>>1)*8;
#pragma unroll
      for (int j = 0; j < 8; ++j) wf.f[j] = ld8(Wswp + nsw*KSW + quad*8 + (k0+j)*32);
    }
    const float bias0 = b1p[n0], bias1 = b1p[n1];
    float bswa = 0.f, bswb = 0.f, bswk = 0.f;
    if (tid < 160){ const int j = tid % 10; bswa = bswp[j]; bswb = bswp[10+j]; bswk = bswp[20+j]; }
    for (int i = tid; i < 512; i += 256) S.g1.c[i] = 0.f;
    if (tid < 160) S.g1.kk[tid] = 0.f;
    for (int i = tid; i < 1024; i += 256) S.g1.smv[i] = sm[(bg*16 + (i>>6))*UU + (i&63)];
    for (int i = tid; i < 960;  i += 256) S.g1.cm[i]  = cmask[(bg*16 + i/60)*SENT + i%60];
    if (sl == 0) S.g1.X1[sb*584 + 575] = 0;
    __syncthreads();

    for (int t = 0; t < TT; ++t){
      if (tid == 0) wait3(cnt0, 16*t, cnt1, 32*(t-3), cnt2, 2*(t-3));
      __syncthreads();
      const u16* h1prev = h1pub + ((t+3)&3)*(BT*HH);
      float sv = (sl < 3) ? strks[((bg*16 + sb)*TT + t)*3 + sl] : 0.f;
      {
        u16x8 a0,a1,a2,a3;
        ld_tile4(h1prev + (bg*16 + sb)*HH + sl*8, a0,a1,a2,a3);
        u16x8* xr = (u16x8*)(S.g1.X1 + sb*584);
        xr[sl] = a0; xr[sl+16] = a1; xr[sl+32] = a2; xr[sl+48] = a3;
        if (sl < 3) S.g1.X1[sb*584 + 512 + sl] = f2bf(sv);
      }
      __syncthreads();
      attn_tail(t, bg, S.g1.X1, 584, 515, S.g1.pp, S.g1.aa, S.g1.bb, S.g1.kk,
                S.g1.phi, S.g1.smv, S.g1.cm, wf, bswa, bswb, bswk, wprev);
      __syncthreads();
      f32x4 acc0 = {0.f,0.f,0.f,0.f}, acc1 = {0.f,0.f,0.f,0.f};
      const u16* ap = S.g1.X1 + l15*584 + quad*8;
#pragma unroll
      for (int kt = 0; kt < 18; ++kt){
        bf16x8 av = ld8(ap + kt*32);
        acc0 = mfma16(av, w1r[2*kt],   acc0);
        acc1 = mfma16(av, w1r[2*kt+1], acc1);
      }
#pragma unroll
      for (int r = 0; r < 4; ++r){
        const int brow = quad*4 + r;
        S.g1.gates[brow*132 + wave*32 + l15]      = acc0[r] + bias0;
        S.g1.gates[brow*132 + wave*32 + 16 + l15] = acc1[r] + bias1;
      }
      __syncthreads();
      u16* h1cur = h1pub + (t&3)*(BT*HH);
      for (int i = tid; i < 512; i += 256){
        const int b = i >> 5, j = i & 31;
        const float* gr = S.g1.gates + b*132 + 4*j;
        float c = sig_(gr[1])*S.g1.c[i] + sig_(gr[0])*tanh_(gr[2]);
        S.g1.c[i] = c;
        st_short_sc(h1cur + (bg*16 + b)*HH + s*32 + j, (u32)f2bf(sig_(gr[3])*tanh_(c)));
      }
      vmwait0();
      __syncthreads();
      if (tid == 0) arrive(cnt0);
    }
  }
  else if (bid < NBG*(G1B+G2B)){
    // ============ role 1: LSTM2 step te = role0 step - 1 ============
    const int b2 = bid - NBG*G1B, bg = b2 >> 5, s = b2 & 31;
    u32* cnt0 = bar + bg*192;
    u32* cnt1 = bar + bg*192 + 64;
    u32* cnt2 = bar + bg*192 + 128;
    bf16x8 w2r[34];
    const int n0 = s*64 + wave*16 + l15;
#pragma unroll
    for (int kt = 0; kt < 34; ++kt) w2r[kt] = ld8(Wp2 + n0*K2P + quad*8 + kt*32);
    WswF wf;
    { const int nsw = (wave&1)*16 + l15, k0 = (wave>>1)*8;
#pragma unroll
      for (int j = 0; j < 8; ++j) wf.f[j] = ld8(Wswp + nsw*KSW + quad*8 + (k0+j)*32);
    }
    const float bias0 = b2p[n0];
    float bswa = 0.f, bswb = 0.f, bswk = 0.f;
    if (tid < 160){ const int j = tid % 10; bswa = bswp[j]; bswb = bswp[10+j]; bswk = bswp[20+j]; }
    S.g2.c[tid] = 0.f;
    if (tid < 160) S.g2.kk[tid] = 0.f;
    for (int i = tid; i < 1024; i += 256) S.g2.smv[i] = sm[(bg*16 + (i>>6))*UU + (i&63)];
    for (int i = tid; i < 960;  i += 256) S.g2.cm[i]  = cmask[(bg*16 + i/60)*SENT + i%60];
    if (sl == 0) S.g2.X2[sb*1096 + 1087] = 0;
    __syncthreads();

    for (int te = 0; te < TT; ++te){
      if (tid == 0) wait3(cnt0, 16*(te+1), cnt1, 32*te, cnt2, 2*(te-3));
      __syncthreads();
      const u16* h1te = h1pub + (te&3)*(BT*HH);
      const u16* h2pv = h2pub + ((te+3)&3)*(BT*HH);
      float sv = (sl < 3) ? strks[((bg*16 + sb)*TT + te)*3 + sl] : 0.f;
      {
        u16x8 a0,a1,a2,a3,b0,b1,b2v,b3;
        ld_tile8(h1te + (bg*16 + sb)*HH + sl*8, h2pv + (bg*16 + sb)*HH + sl*8,
                 a0,a1,a2,a3, b0,b1,b2v,b3);
        u16x8* xr = (u16x8*)(S.g2.X2 + sb*1096);
        xr[sl] = a0; xr[sl+16] = a1; xr[sl+32] = a2; xr[sl+48] = a3;
        xr[64+sl] = b0; xr[64+sl+16] = b1; xr[64+sl+32] = b2v; xr[64+sl+48] = b3;
        if (sl < 3) S.g2.X2[sb*1096 + 1024 + sl] = f2bf(sv);
      }
      __syncthreads();
      attn_tail(te+1, bg, S.g2.X2, 1096, 1027, S.g2.pp, S.g2.aa, S.g2.bb, S.g2.kk,
                S.g2.phi, S.g2.smv, S.g2.cm, wf, bswa, bswb, bswk, wprev);
      __syncthreads();
      f32x4 acc = {0.f,0.f,0.f,0.f};
      const u16* ap = S.g2.X2 + l15*1096 + quad*8;
#pragma unroll
      for (int kt = 0; kt < 34; ++kt) acc = mfma16(ld8(ap + kt*32), w2r[kt], acc);
#pragma unroll
      for (int r = 0; r < 4; ++r)
        S.g2.gates[(quad*4 + r)*68 + wave*16 + l15] = acc[r] + bias0;
      __syncthreads();
      u16* h2cur = h2pub + (te&3)*(BT*HH);
      {
        const int b = tid >> 4, j = tid & 15;
        const float* gr = S.g2.gates + b*68 + 4*j;
        float c = sig_(gr[1])*S.g2.c[tid] + sig_(gr[0])*tanh_(gr[2]);
        S.g2.c[tid] = c;
        st_short_sc(h2cur + (bg*16 + b)*HH + s*16 + j, (u32)f2bf(sig_(gr[3])*tanh_(c)));
      }
      vmwait0();
      __syncthreads();
      if (tid == 0) arrive(cnt1);
    }
  }
  else {
    // ============ role 2: MDN head, step te (signals after staging) ====
    const int b2 = bid - NBG*(G1B+G2B), bg = b2 >> 1, s = b2 & 1;
    u32* cnt1 = bar + bg*192 + 64;
    u32* cnt2 = bar + bg*192 + 128;
    bf16x8 wmr[32];
    const int n0 = s*64 + wave*16 + l15;
#pragma unroll
    for (int kt = 0; kt < 32; ++kt) wmr[kt] = ld8(Wmdp + n0*KMD + quad*8 + kt*32);
    const float bias0 = bmdp[n0];
    __syncthreads();

    for (int te = 0; te < TT; ++te){
      if (tid == 0) wait1(cnt1, 32*(te+1));
      __syncthreads();
      const u16* h1te = h1pub + (te&3)*(BT*HH);
      const u16* h2te = h2pub + (te&3)*(BT*HH);
      {
        u16x8 a0,a1,a2,a3,b0,b1,b2v,b3;
        ld_tile8(h1te + (bg*16 + sb)*HH + sl*8, h2te + (bg*16 + sb)*HH + sl*8,
                 a0,a1,a2,a3, b0,b1,b2v,b3);
        u16x8* xr = (u16x8*)(S.md.X + sb*1032);
        xr[sl] = a0; xr[sl+16] = a1; xr[sl+32] = a2; xr[sl+48] = a3;
        xr[64+sl] = b0; xr[64+sl+16] = b1; xr[64+sl+32] = b2v; xr[64+sl+48] = b3;
      }
      __syncthreads();
      if (tid == 0) arrive(cnt2);    // ring reads done — unblock producers
      f32x4 acc = {0.f,0.f,0.f,0.f};
      const u16* ap = S.md.X + l15*1032 + quad*8;
#pragma unroll
      for (int kt = 0; kt < 32; ++kt) acc = mfma16(ld8(ap + kt*32), wmr[kt], acc);
#pragma unroll
      for (int r = 0; r < 4; ++r)
        S.md.par[(quad*4 + r)*68 + wave*16 + l15] = acc[r] + bias0;
      __syncthreads();
      for (int i = tid; i < 1024; i += 256){
        const int b = i >> 6, lc = i & 63, gc = s*64 + lc;
        const int bt = (bg*16 + b)*TT + te;
        const float v = S.md.par[b*68 + lc];
        if (gc >= 20 && gc < 40)        out[OW_MU1 + bt*20 + (gc-20)]  = v;
        else if (gc >= 40 && gc < 60)   out[OW_MU2 + bt*20 + (gc-40)]  = v;
        else if (gc >= 60 && gc < 80)   out[OW_S1  + bt*20 + (gc-60)]  = __expf(v);
        else if (gc >= 80 && gc < 100)  out[OW_S2  + bt*20 + (gc-80)]  = __expf(v);
        else if (gc >= 100 && gc < 120) out[OW_RHO + bt*20 + (gc-100)] = tanh_(v);
        else if (gc == 120)             out[OW_EOS + bt]               = sig_(v);
      }
      if (s == 0 && tid < 16){
        const int b = tid;
        const int bt = (bg*16 + b)*TT + te;
        float mx = -1e30f;
        for (int c = 0; c < 20; ++c) mx = fmaxf(mx, S.md.par[b*68 + c]);
        float sum = 0.f;
        for (int c = 0; c < 20; ++c) sum += __expf(S.md.par[b*68 + c] - mx);
        const float inv = 1.f/sum;
        for (int c = 0; c < 20; ++c)
          out[OW_W + bt*20 + c] = __expf(S.md.par[b*68 + c] - mx)*inv;
      }
    }
  }
}

extern "C" void kernel_launch(void* const* d_in, const int* in_sizes, int n_in,
                              void* d_out, int out_size, void* d_ws, size_t ws_size,
                              hipStream_t stream)
{
  const float* strks   = (const float*)d_in[0];
  const float* sentsm  = (const float*)d_in[3];
  const float* onehots = (const float*)d_in[4];
  const float* wprev   = (const float*)d_in[5];
  const float* Wih1 = (const float*)d_in[6];
  const float* Whh1 = (const float*)d_in[7];
  const float* bih1 = (const float*)d_in[8];
  const float* bhh1 = (const float*)d_in[9];
  const float* Wih2 = (const float*)d_in[10];
  const float* Whh2 = (const float*)d_in[11];
  const float* bih2 = (const float*)d_in[12];
  const float* bhh2 = (const float*)d_in[13];
  const float* Wsw  = (const float*)d_in[14];
  const float* bsw  = (const float*)d_in[15];
  const float* Wmdn = (const float*)d_in[16];
  const float* bmdn = (const float*)d_in[17];
  (void)in_sizes; (void)n_in; (void)out_size;

  if (ws_size < (size_t)WS_NEED) return;

  hipMemsetAsync(d_ws, 0, ZERO_BYTES, stream);
  pack_kernel<<<2048, 256, 0, stream>>>(Wih1, Whh1, bih1, bhh1, Wih2, Whh2, bih2, bhh2,
                                        Wsw, bsw, Wmdn, bmdn, onehots, (char*)d_ws);
  rnn_main<<<NBLK, 256, 0, stream>>>(strks, sentsm, wprev, (char*)d_ws, (float*)d_out);
}